// Round 11
// baseline (325.097 us; speedup 1.0000x reference)
//
#include <hip/hip_runtime.h>
#include <hip/hip_bf16.h>
#include <math.h>

#define EPSF 1e-5f

typedef __bf16 v8bf __attribute__((ext_vector_type(8)));
typedef float  v4f  __attribute__((ext_vector_type(4)));
typedef unsigned int u32;
typedef unsigned short u16;

__device__ __forceinline__ float gelu_exact(float x) {
    return 0.5f * x * (1.0f + erff(x * 0.70710678f));
}
__device__ __forceinline__ u16 f2bf(float f) {   // RNE
    u32 u = __float_as_uint(f);
    return (u16)((u + 0x7fffu + ((u >> 16) & 1u)) >> 16);
}
__device__ __forceinline__ float bf2f(u16 u) {
    return __uint_as_float(((u32)u) << 16);
}
__device__ __forceinline__ void gload16(const void* g, void* l) {
    __builtin_amdgcn_global_load_lds((const __attribute__((address_space(1))) u32*)g,
                                     (__attribute__((address_space(3))) u32*)l, 16, 0, 0);
}

// counted-vmcnt barrier: allow N vector-mem ops outstanding, drain LDS ops.
#define BARRIER(N) do { \
    asm volatile("s_waitcnt vmcnt(" #N ") lgkmcnt(0)" ::: "memory"); \
    __builtin_amdgcn_s_barrier(); \
} while (0)

// ---------------------------------------------------------------------------
// Prep: fz_w[o][1536] f32 -> Bz[ec2][h][n][8] bf16 (coalesced reads)
// ---------------------------------------------------------------------------
__global__ __launch_bounds__(256) void kprep_z(const float* __restrict__ fz_w,
                                               u16* __restrict__ Bz) {
    int idx = blockIdx.x * 256 + threadIdx.x;   // 0 .. 73727
    int n = idx / 192;
    int r = idx % 192;
    int ec2 = r >> 2;
    int h = r & 3;
    const float* src = fz_w + (size_t)n * 1536 + ec2 * 32 + h * 8;
    float4 v0 = *(const float4*)src;
    float4 v1 = *(const float4*)(src + 4);
    uint4 pk;
    pk.x = (u32)f2bf(v0.x) | ((u32)f2bf(v0.y) << 16);
    pk.y = (u32)f2bf(v0.z) | ((u32)f2bf(v0.w) << 16);
    pk.z = (u32)f2bf(v1.x) | ((u32)f2bf(v1.y) << 16);
    pk.w = (u32)f2bf(v1.z) | ((u32)f2bf(v1.w) << 16);
    size_t slot = ((size_t)(ec2 * 4 + h) * 384 + n);
    *(uint4*)(Bz + slot * 8) = pk;
}

// ---------------------------------------------------------------------------
// Prep: w[n][e][3][3] f32 -> Bw[conv][s][ec2][h][n][8] bf16.
// ---------------------------------------------------------------------------
__global__ __launch_bounds__(256) void kprep_w(const float* __restrict__ wr,
                                               const float* __restrict__ wi,
                                               u16* __restrict__ Bw) {
    __shared__ float wsm[6912];
    const int tid = threadIdx.x;
    const int n = blockIdx.x >> 1;
    const int conv = blockIdx.x & 1;
    const float* w = (conv ? wi : wr) + (size_t)n * 6912;
#pragma unroll
    for (int k = 0; k < 7; ++k) {
        int sl = tid + k * 256;
        if (sl < 1728) ((float4*)wsm)[sl] = ((const float4*)w)[sl];
    }
    __syncthreads();
#pragma unroll
    for (int k = 0; k < 4; ++k) {
        int sl = tid + k * 256;          // (s*24+ec2)*4 + h
        if (sl < 864) {
            int h = sl & 3;
            int r = sl >> 2;
            int ec2 = r % 24;
            int s = r / 24;
            int ch0 = ec2 * 32 + h * 8;
            u16 tmp[8];
#pragma unroll
            for (int e = 0; e < 8; ++e) tmp[e] = f2bf(wsm[(ch0 + e) * 9 + s]);
            uint4 pk;
            pk.x = (u32)tmp[0] | ((u32)tmp[1] << 16);
            pk.y = (u32)tmp[2] | ((u32)tmp[3] << 16);
            pk.z = (u32)tmp[4] | ((u32)tmp[5] << 16);
            pk.w = (u32)tmp[6] | ((u32)tmp[7] << 16);
            size_t slot = ((size_t)conv * 864 + sl) * 384 + n;
            *(uint4*)(Bw + slot * 8) = pk;
        }
    }
}

// ---------------------------------------------------------------------------
// kz2: z = gelu(LN(concat(z_r,z_i) @ fz_w^T + fz_b)) via MFMA.
// grid (2 t-halves, 128 b), 384 thr = 6 waves. Writes zpk[b][o][t(64)] bf16.
// ---------------------------------------------------------------------------
#define ZB_BUF 24576
#define ZA_BUF 2048

__global__ __launch_bounds__(384, 1) void kz2(const float* __restrict__ z_r,
                                              const float* __restrict__ z_i,
                                              const u16* __restrict__ Bz,
                                              const float* __restrict__ fz_b,
                                              const float* __restrict__ ln_g,
                                              const float* __restrict__ ln_b,
                                              u16* __restrict__ zpk) {
    const int th = blockIdx.x;
    const int b  = blockIdx.y;
    const int tid  = threadIdx.x;
    const int lane = tid & 63;
    const int wid  = tid >> 6;
    const int l15  = lane & 15;
    const int h    = lane >> 4;

    __shared__ __align__(16) char lds[3 * ZB_BUF + 2 * ZA_BUF];   // 77824
    char* ldsZB = lds;
    char* ldsZA = lds + 3 * ZB_BUF;
    __shared__ float redS[6 * 32], redQ[6 * 32], mu_s[32], rs_s[32];

    const float* zr_b = z_r + (size_t)b * (64 * 768);
    const float* zi_b = z_i + (size_t)b * (64 * 768);

    int boff[4];
#pragma unroll
    for (int nj = 0; nj < 4; ++nj) {
        int n = wid * 64 + nj * 16 + l15;
        boff[nj] = h * 6144 + n * 16;
    }
    int zaoff[2];
#pragma unroll
    for (int mi = 0; mi < 2; ++mi)
        zaoff[mi] = h * 512 + (mi * 16 + l15) * 16;

    auto stageZB = [&](int ec2, char* buf) {       // 4 gload16 / thread
        const char* src = (const char*)(Bz + (size_t)ec2 * 1536 * 8);
#pragma unroll
        for (int k = 0; k < 4; ++k) {
            int sl = tid + k * 384;
            gload16(src + sl * 16, buf + sl * 16);
        }
    };
    auto issueZA = [&](int ec2, float4* zr) {      // 1 load / thread (uniform)
        const float* zsrc = (ec2 < 24) ? zr_b : zi_b;
        const int ch0 = (ec2 < 24 ? ec2 : ec2 - 24) * 32;
        int sl = tid & 255;
        int row = sl >> 3, qq = sl & 7;
        zr[0] = *(const float4*)(zsrc + (size_t)(th * 32 + row) * 768 + ch0 + qq * 4);
    };
    auto convertZA = [&](const float4* zr, char* buf) {
        int sl = tid & 255;
        int row = sl >> 3, qq = sl & 7;
        ushort4 pk;
        pk.x = f2bf(zr[0].x); pk.y = f2bf(zr[0].y);
        pk.z = f2bf(zr[0].z); pk.w = f2bf(zr[0].w);
        *(ushort4*)(buf + (qq >> 1) * 512 + row * 16 + (qq & 1) * 8) = pk;
    };

    v4f acc[2][4] = {};

    auto comp = [&](char* curA, char* curB) {
        v8bf a[2], bfv[4];
#pragma unroll
        for (int mi = 0; mi < 2; ++mi) a[mi] = *(const v8bf*)(curA + zaoff[mi]);
#pragma unroll
        for (int nj = 0; nj < 4; ++nj) bfv[nj] = *(const v8bf*)(curB + boff[nj]);
        __builtin_amdgcn_s_setprio(1);
#pragma unroll
        for (int mi = 0; mi < 2; ++mi)
#pragma unroll
            for (int nj = 0; nj < 4; ++nj)
                acc[mi][nj] = __builtin_amdgcn_mfma_f32_16x16x32_bf16(a[mi], bfv[nj], acc[mi][nj], 0, 0, 0);
        __builtin_amdgcn_s_setprio(0);
    };

    float4 zreg[1];
    {
        issueZA(0, zreg);
        stageZB(0, ldsZB);
        stageZB(1, ldsZB + ZB_BUF);
        convertZA(zreg, ldsZA);      // waits ZA(0)
        issueZA(1, zreg);
        BARRIER(5);                  // allow ZB(1)=4 + ZA(1)=1
    }
#pragma unroll 1
    for (int t = 0; t < 46; ++t) {
        stageZB(t + 2, ldsZB + ((t + 2) % 3) * ZB_BUF);
        comp(ldsZA + (t & 1) * ZA_BUF, ldsZB + (t % 3) * ZB_BUF);
        convertZA(zreg, ldsZA + ((t + 1) & 1) * ZA_BUF);  // waits ZA(t+1): vmcnt(4)
        issueZA(t + 2, zreg);
        BARRIER(5);                  // allow ZB(t+2)=4 + ZA(t+2)=1; drains ZB(t+1)
    }
    {   // t = 46
        comp(ldsZA + (46 & 1) * ZA_BUF, ldsZB + (46 % 3) * ZB_BUF);
        convertZA(zreg, ldsZA + (47 & 1) * ZA_BUF);       // waits ZA(47): vmcnt(0)
        BARRIER(0);
    }
    comp(ldsZA + (47 & 1) * ZA_BUF, ldsZB + (47 % 3) * ZB_BUF);

    // ---- bias + LN stats (rows 0..31 local) ----
    float fzb[4], lng[4], lnb[4];
#pragma unroll
    for (int nj = 0; nj < 4; ++nj) {
        int o = wid * 64 + nj * 16 + l15;
        fzb[nj] = fz_b[o]; lng[nj] = ln_g[o]; lnb[nj] = ln_b[o];
    }
#pragma unroll
    for (int mi = 0; mi < 2; ++mi)
#pragma unroll
        for (int nj = 0; nj < 4; ++nj)
#pragma unroll
            for (int reg = 0; reg < 4; ++reg)
                acc[mi][nj][reg] += fzb[nj];

#pragma unroll
    for (int mi = 0; mi < 2; ++mi) {
#pragma unroll
        for (int reg = 0; reg < 4; ++reg) {
            float s = 0.f, q = 0.f;
#pragma unroll
            for (int nj = 0; nj < 4; ++nj) {
                float v = acc[mi][nj][reg];
                s += v; q += v * v;
            }
#pragma unroll
            for (int m = 0; m < 4; ++m) {
                s += __shfl_xor(s, 1 << m, 64);
                q += __shfl_xor(q, 1 << m, 64);
            }
            if (l15 == 0) {
                int row = mi * 16 + h * 4 + reg;
                redS[wid * 32 + row] = s;
                redQ[wid * 32 + row] = q;
            }
        }
    }
    __syncthreads();
    if (tid < 32) {
        float s = 0.f, q = 0.f;
#pragma unroll
        for (int w6 = 0; w6 < 6; ++w6) { s += redS[w6 * 32 + tid]; q += redQ[w6 * 32 + tid]; }
        float mu = s * (1.0f / 384.0f);
        float var = q * (1.0f / 384.0f) - mu * mu;
        mu_s[tid] = mu;
        rs_s[tid] = rsqrtf(var + EPSF);
    }
    __syncthreads();

    // ---- LN + gelu -> zpk[b][o][t] ----
#pragma unroll
    for (int mi = 0; mi < 2; ++mi)
#pragma unroll
        for (int nj = 0; nj < 4; ++nj) {
            int o = wid * 64 + nj * 16 + l15;
            u32* dst = (u32*)zpk + ((size_t)b * 384 + o) * 32 + th * 16 + mi * 8 + h * 2;
#pragma unroll
            for (int rp = 0; rp < 2; ++rp) {
                float zv[2];
#pragma unroll
                for (int k = 0; k < 2; ++k) {
                    int reg = rp * 2 + k;
                    int row = mi * 16 + h * 4 + reg;
                    float v = (acc[mi][nj][reg] - mu_s[row]) * rs_s[row] * lng[nj] + lnb[nj];
                    zv[k] = gelu_exact(v);
                }
                dst[rp] = (u32)f2bf(zv[0]) | ((u32)f2bf(zv[1]) << 16);
            }
        }
}

// ---------------------------------------------------------------------------
// kc8: implicit-GEMM cropped conv, batch-paired, 2 blocks/CU.
// grid 256 flat (XCD-swizzled -> q=conv*2+nh, bp), 384 thr = 6 waves (2m x 3n),
// wave tile 64x64 (F/B=32). M=128 (2 batches), N=192, K=6912 (216 steps).
// LDS 72.4 KB: A single buffer (republished per ec2) + 4-slot B ring
// (3-step lookahead). Counted-vmcnt ledger, in-order retirement.
// ---------------------------------------------------------------------------
#define APL8   2848              // A plane stride (176*16 + 32)
#define ABAT8  (4 * APL8)        // 11392 per batch
#define ABUF8  (2 * ABAT8)       // 22784
#define PBP8   3104              // B plane stride (192*16 + 32)
#define BSLOT8 (4 * PBP8)        // 12416

__global__ __launch_bounds__(384, 3) void kc8(const float* __restrict__ x_r,
                                              const float* __restrict__ x_i,
                                              const u16* __restrict__ Bw,
                                              const u16* __restrict__ zpk,
                                              const float* __restrict__ br,  const float* __restrict__ bnr_g,
                                              const float* __restrict__ bnr_b, const float* __restrict__ bnr_m,
                                              const float* __restrict__ bnr_v,
                                              const float* __restrict__ bi,  const float* __restrict__ bni_g,
                                              const float* __restrict__ bni_b, const float* __restrict__ bni_m,
                                              const float* __restrict__ bni_v,
                                              float* __restrict__ part) {
    // XCD-swizzle: each XCD (consecutive flat ids round-robin) keeps one q.
    const int flat = blockIdx.x;        // 0..255
    const int xcd  = flat & 7;
    const int idx  = flat >> 3;         // 0..31
    const int q    = xcd >> 1;          // 0..3 = conv*2+nh
    const int bp   = idx * 2 + (xcd & 1);   // 0..63
    const int conv = q >> 1;
    const int nh   = q & 1;
    const int tid  = threadIdx.x;
    const int lane = tid & 63;
    const int wid  = tid >> 6;          // 0..5
    const int wm   = wid / 3;           // 0..1 batch
    const int wn   = wid % 3;           // 0..2 64-col group
    const int l15  = lane & 15;
    const int h    = lane >> 4;         // 0..3

    __shared__ __align__(16) char ldsA[ABUF8];        // 22784
    __shared__ __align__(16) char ldsB[4 * BSLOT8];   // 49664
    __shared__ float redF[6];

    const float* x   = conv ? x_i : x_r;
    const float* xb0 = x + (size_t)(bp * 2 + 0) * (256 * 768);
    const float* xb1 = x + (size_t)(bp * 2 + 1) * (256 * 768);

    int boff[4];
#pragma unroll
    for (int nj = 0; nj < 4; ++nj) {
        int nl = wn * 64 + nj * 16 + l15;
        boff[nj] = h * PBP8 + nl * 16;
    }
    int aoff[4];
#pragma unroll
    for (int mi = 0; mi < 4; ++mi) {
        int p = mi * 16 + l15;
        int i = p >> 3, j = p & 7;
        aoff[mi] = wm * ABAT8 + h * APL8 + (i * 16 + j + 3) * 16;
    }

    auto stageB = [&](int e2, int s2, char* buf) {   // 2 gload16 / thread
        const char* base = (const char*)Bw +
            (((size_t)conv * 864 + ((size_t)s2 * 24 + e2) * 4) * 384) * 16;
#pragma unroll
        for (int k = 0; k < 2; ++k) {
            int sl = tid + k * 384;      // 0..767 = hh*192 + nl
            int hh = sl / 192;
            int nl = sl - hh * 192;
            gload16(base + ((size_t)hh * 384 + nh * 192 + nl) * 16,
                    buf + hh * PBP8 + nl * 16);
        }
    };
    auto issueA = [&](int ec2, float4* ar) {         // 8 loads/thread (wrapped)
#pragma unroll
        for (int k = 0; k < 8; ++k) {
            int sl = tid + k * 384;
            if (sl >= 2816) sl -= 2816;
            int batch = (sl >= 1408) ? 1 : 0;
            int r2 = sl - batch * 1408;
            int row = r2 >> 3, qq = r2 & 7;
            const float* xb = batch ? xb1 : xb0;
            ar[k] = *(const float4*)(xb + (size_t)(48 + row) * 768 + ec2 * 32 + qq * 4);
        }
    };
    auto convertA = [&](const float4* ar, char* buf) {
#pragma unroll
        for (int k = 0; k < 8; ++k) {
            int sl = tid + k * 384;
            if (sl >= 2816) sl -= 2816;
            int batch = (sl >= 1408) ? 1 : 0;
            int r2 = sl - batch * 1408;
            int row = r2 >> 3, qq = r2 & 7;
            ushort4 pk;
            pk.x = f2bf(ar[k].x); pk.y = f2bf(ar[k].y);
            pk.z = f2bf(ar[k].z); pk.w = f2bf(ar[k].w);
            *(ushort4*)(buf + batch * ABAT8 + (qq >> 1) * APL8 + row * 16 + (qq & 1) * 8) = pk;
        }
    };

    v4f acc[4][4] = {};

    auto comp = [&](int soff, char* curB) {
        v8bf a[4], bfv[4];
#pragma unroll
        for (int mi = 0; mi < 4; ++mi) a[mi] = *(const v8bf*)(ldsA + aoff[mi] + soff);
#pragma unroll
        for (int nj = 0; nj < 4; ++nj) bfv[nj] = *(const v8bf*)(curB + boff[nj]);
        __builtin_amdgcn_s_setprio(1);
#pragma unroll
        for (int mi = 0; mi < 4; ++mi)
#pragma unroll
            for (int nj = 0; nj < 4; ++nj)
                acc[mi][nj] = __builtin_amdgcn_mfma_f32_16x16x32_bf16(a[mi], bfv[nj], acc[mi][nj], 0, 0, 0);
        __builtin_amdgcn_s_setprio(0);
    };

    float4 areg[8];
    {   // prologue: A(0) issued first (oldest), B(0..2) staged behind it.
        issueA(0, areg);
        stageB(0, 0, ldsB + 0 * BSLOT8);
        stageB(0, 1, ldsB + 1 * BSLOT8);
        stageB(0, 2, ldsB + 2 * BSLOT8);
        convertA(areg, ldsA);            // reg-dep waits areg only (B newer)
        BARRIER(4);                      // drain B(0); B(1),B(2) in flight
    }

    // step g = ec2*9+s: read slot (ec2+s)&3, stage B(g+3) into (ec2+s+3)&3.
#pragma unroll 1
    for (int ec2 = 0; ec2 < 24; ++ec2) {
        const bool lastE = (ec2 == 23);
#pragma unroll
        for (int s = 0; s < 9; ++s) {
            if (!lastE || s <= 5) {      // stage B(g+3)
                int e2 = (s <= 5) ? ec2 : ec2 + 1;
                int s2 = (s <= 5) ? s + 3 : s - 6;
                stageB(e2, s2, ldsB + ((ec2 + s + 3) & 3) * BSLOT8);
            }
            if (s == 1 && !lastE) {
                __builtin_amdgcn_sched_barrier(0);   // keep issueA after stageB
                issueA(ec2 + 1, areg);
            }
            comp(((s / 3) * 16 + (s % 3)) * 16, ldsB + ((ec2 + s) & 3) * BSLOT8);
            if (!lastE) {
                if (s >= 1 && s <= 3) BARRIER(12);   // B queue + areg(8) behind
                else if (s == 8) {
                    BARRIER(4);                      // drain B(g+1); keep B(g+2,3)
                    convertA(areg, ldsA);            // areg retired at s==4
                    BARRIER(4);                      // publish A ds_writes
                } else BARRIER(4);                   // s==4 drains areg too
            } else {
                if (s <= 5)      BARRIER(4);
                else if (s == 6) BARRIER(2);
                else if (s == 7) BARRIER(0);
                // s == 8: fall through to epilogue
            }
        }
    }

    // ---- BN + gelu + dot(zpk) ----
    const float* bcp = conv ? bi    : br;
    const float* gp  = conv ? bni_g : bnr_g;
    const float* bbp = conv ? bni_b : bnr_b;
    const float* mp  = conv ? bni_m : bnr_m;
    const float* vp  = conv ? bni_v : bnr_v;
    const int batch = bp * 2 + wm;

    float sum = 0.f;
#pragma unroll
    for (int nj = 0; nj < 4; ++nj) {
        const int o = nh * 192 + wn * 64 + nj * 16 + l15;
        const float sc = gp[o] * rsqrtf(vp[o] + EPSF);
        const float sh2 = (bcp[o] - mp[o]) * sc + bbp[o];
        const u16* zb = zpk + ((size_t)batch * 384 + o) * 64;
#pragma unroll
        for (int mi = 0; mi < 4; ++mi) {
            ushort4 zw = *(const ushort4*)(zb + mi * 16 + h * 4);
#pragma unroll
            for (int reg = 0; reg < 4; ++reg) {
                float y = fmaf(acc[mi][nj][reg], sc, sh2);
                u16 zu = (reg == 0) ? zw.x : (reg == 1) ? zw.y : (reg == 2) ? zw.z : zw.w;
                sum = fmaf(gelu_exact(y), bf2f(zu), sum);
            }
        }
    }
#pragma unroll
    for (int off = 32; off >= 1; off >>= 1) sum += __shfl_down(sum, off, 64);

    if (lane == 0) redF[wid] = sum;
    __syncthreads();
    if (tid == 0) {
        float t0 = redF[0] + redF[1] + redF[2];
        float t1 = redF[3] + redF[4] + redF[5];
        part[((size_t)conv * 128 + bp * 2 + 0) * 2 + nh] = t0;
        part[((size_t)conv * 128 + bp * 2 + 1) * 2 + nh] = t1;
    }
}

// ---------------------------------------------------------------------------
// kr: combine n-half partials, sigmoid.
// ---------------------------------------------------------------------------
__global__ __launch_bounds__(256) void kr(const float* __restrict__ part,
                                          const float* __restrict__ c,
                                          float* __restrict__ out) {
    int v = threadIdx.x;     // 0..255 = conv*128+b
    float s = part[v * 2] + part[v * 2 + 1];
    out[v] = 1.f / (1.f + expf(-s / c[0]));
}

extern "C" void kernel_launch(void* const* d_in, const int* in_sizes, int n_in,
                              void* d_out, int out_size, void* d_ws, size_t ws_size,
                              hipStream_t stream) {
    const float* z_r   = (const float*)d_in[0];
    const float* z_i   = (const float*)d_in[1];
    const float* x_r   = (const float*)d_in[2];
    const float* x_i   = (const float*)d_in[3];
    const float* fz_w  = (const float*)d_in[4];
    const float* fz_b  = (const float*)d_in[5];
    const float* ln_g  = (const float*)d_in[6];
    const float* ln_b  = (const float*)d_in[7];
    const float* wr    = (const float*)d_in[8];
    const float* br    = (const float*)d_in[9];
    const float* bnr_g = (const float*)d_in[10];
    const float* bnr_b = (const float*)d_in[11];
    const float* bnr_m = (const float*)d_in[12];
    const float* bnr_v = (const float*)d_in[13];
    const float* wi    = (const float*)d_in[14];
    const float* bi    = (const float*)d_in[15];
    const float* bni_g = (const float*)d_in[16];
    const float* bni_b = (const float*)d_in[17];
    const float* bni_m = (const float*)d_in[18];
    const float* bni_v = (const float*)d_in[19];
    const float* c     = (const float*)d_in[20];

    // ws (bytes): Bz [0, 1179648) | Bw [+10616832) | zpk [+6291456) | part [+2048)
    u16*   Bz   = (u16*)d_ws;
    u16*   Bw   = (u16*)((char*)d_ws + 1179648);
    u16*   zpk  = (u16*)((char*)d_ws + 1179648 + 10616832);
    float* part = (float*)((char*)d_ws + 1179648 + 10616832 + 6291456);

    kprep_z<<<288, 256, 0, stream>>>(fz_w, Bz);
    kprep_w<<<768, 256, 0, stream>>>(wr, wi, Bw);
    kz2<<<dim3(2, 128), 384, 0, stream>>>(z_r, z_i, Bz, fz_b, ln_g, ln_b, zpk);
    kc8<<<256, 384, 0, stream>>>(x_r, x_i, Bw, zpk,
                                 br, bnr_g, bnr_b, bnr_m, bnr_v,
                                 bi, bni_g, bni_b, bni_m, bni_v,
                                 part);
    kr<<<1, 256, 0, stream>>>(part, c, (float*)d_out);
}

// Round 12
// 242.226 us; speedup vs baseline: 1.3421x; 1.3421x over previous
//
#include <hip/hip_runtime.h>
#include <hip/hip_bf16.h>
#include <math.h>

#define EPSF 1e-5f

typedef __bf16 v8bf __attribute__((ext_vector_type(8)));
typedef float  v4f  __attribute__((ext_vector_type(4)));
typedef unsigned int u32;
typedef unsigned short u16;

__device__ __forceinline__ float gelu_exact(float x) {
    return 0.5f * x * (1.0f + erff(x * 0.70710678f));
}
__device__ __forceinline__ u16 f2bf(float f) {   // RNE
    u32 u = __float_as_uint(f);
    return (u16)((u + 0x7fffu + ((u >> 16) & 1u)) >> 16);
}
__device__ __forceinline__ float bf2f(u16 u) {
    return __uint_as_float(((u32)u) << 16);
}
__device__ __forceinline__ void gload16(const void* g, void* l) {
    __builtin_amdgcn_global_load_lds((const __attribute__((address_space(1))) u32*)g,
                                     (__attribute__((address_space(3))) u32*)l, 16, 0, 0);
}

// counted-vmcnt barrier: allow N vector-mem ops outstanding, drain LDS ops.
#define BARRIER(N) do { \
    asm volatile("s_waitcnt vmcnt(" #N ") lgkmcnt(0)" ::: "memory"); \
    __builtin_amdgcn_s_barrier(); \
} while (0)

// ---------------------------------------------------------------------------
// Prep: fz_w[o][1536] f32 -> Bz[ec2][h][n][8] bf16 (coalesced reads)
// ---------------------------------------------------------------------------
__global__ __launch_bounds__(256) void kprep_z(const float* __restrict__ fz_w,
                                               u16* __restrict__ Bz) {
    int idx = blockIdx.x * 256 + threadIdx.x;   // 0 .. 73727
    int n = idx / 192;
    int r = idx % 192;
    int ec2 = r >> 2;
    int h = r & 3;
    const float* src = fz_w + (size_t)n * 1536 + ec2 * 32 + h * 8;
    float4 v0 = *(const float4*)src;
    float4 v1 = *(const float4*)(src + 4);
    uint4 pk;
    pk.x = (u32)f2bf(v0.x) | ((u32)f2bf(v0.y) << 16);
    pk.y = (u32)f2bf(v0.z) | ((u32)f2bf(v0.w) << 16);
    pk.z = (u32)f2bf(v1.x) | ((u32)f2bf(v1.y) << 16);
    pk.w = (u32)f2bf(v1.z) | ((u32)f2bf(v1.w) << 16);
    size_t slot = ((size_t)(ec2 * 4 + h) * 384 + n);
    *(uint4*)(Bz + slot * 8) = pk;
}

// ---------------------------------------------------------------------------
// Prep: w[n][e][3][3] f32 -> Bw[conv][s][ec2][h][n][8] bf16.
// ---------------------------------------------------------------------------
__global__ __launch_bounds__(256) void kprep_w(const float* __restrict__ wr,
                                               const float* __restrict__ wi,
                                               u16* __restrict__ Bw) {
    __shared__ float wsm[6912];
    const int tid = threadIdx.x;
    const int n = blockIdx.x >> 1;
    const int conv = blockIdx.x & 1;
    const float* w = (conv ? wi : wr) + (size_t)n * 6912;
#pragma unroll
    for (int k = 0; k < 7; ++k) {
        int sl = tid + k * 256;
        if (sl < 1728) ((float4*)wsm)[sl] = ((const float4*)w)[sl];
    }
    __syncthreads();
#pragma unroll
    for (int k = 0; k < 4; ++k) {
        int sl = tid + k * 256;          // (s*24+ec2)*4 + h
        if (sl < 864) {
            int h = sl & 3;
            int r = sl >> 2;
            int ec2 = r % 24;
            int s = r / 24;
            int ch0 = ec2 * 32 + h * 8;
            u16 tmp[8];
#pragma unroll
            for (int e = 0; e < 8; ++e) tmp[e] = f2bf(wsm[(ch0 + e) * 9 + s]);
            uint4 pk;
            pk.x = (u32)tmp[0] | ((u32)tmp[1] << 16);
            pk.y = (u32)tmp[2] | ((u32)tmp[3] << 16);
            pk.z = (u32)tmp[4] | ((u32)tmp[5] << 16);
            pk.w = (u32)tmp[6] | ((u32)tmp[7] << 16);
            size_t slot = ((size_t)conv * 864 + sl) * 384 + n;
            *(uint4*)(Bw + slot * 8) = pk;
        }
    }
}

// ---------------------------------------------------------------------------
// kz2: z = gelu(LN(concat(z_r,z_i) @ fz_w^T + fz_b)) via MFMA.
// grid (2 t-halves, 128 b), 384 thr = 6 waves. Writes zpk[b][o][t(64)] bf16.
// ---------------------------------------------------------------------------
#define ZB_BUF 24576
#define ZA_BUF 2048

__global__ __launch_bounds__(384, 1) void kz2(const float* __restrict__ z_r,
                                              const float* __restrict__ z_i,
                                              const u16* __restrict__ Bz,
                                              const float* __restrict__ fz_b,
                                              const float* __restrict__ ln_g,
                                              const float* __restrict__ ln_b,
                                              u16* __restrict__ zpk) {
    const int th = blockIdx.x;
    const int b  = blockIdx.y;
    const int tid  = threadIdx.x;
    const int lane = tid & 63;
    const int wid  = tid >> 6;
    const int l15  = lane & 15;
    const int h    = lane >> 4;

    __shared__ __align__(16) char lds[3 * ZB_BUF + 2 * ZA_BUF];   // 77824
    char* ldsZB = lds;
    char* ldsZA = lds + 3 * ZB_BUF;
    __shared__ float redS[6 * 32], redQ[6 * 32], mu_s[32], rs_s[32];

    const float* zr_b = z_r + (size_t)b * (64 * 768);
    const float* zi_b = z_i + (size_t)b * (64 * 768);

    int boff[4];
#pragma unroll
    for (int nj = 0; nj < 4; ++nj) {
        int n = wid * 64 + nj * 16 + l15;
        boff[nj] = h * 6144 + n * 16;
    }
    int zaoff[2];
#pragma unroll
    for (int mi = 0; mi < 2; ++mi)
        zaoff[mi] = h * 512 + (mi * 16 + l15) * 16;

    auto stageZB = [&](int ec2, char* buf) {       // 4 gload16 / thread
        const char* src = (const char*)(Bz + (size_t)ec2 * 1536 * 8);
#pragma unroll
        for (int k = 0; k < 4; ++k) {
            int sl = tid + k * 384;
            gload16(src + sl * 16, buf + sl * 16);
        }
    };
    auto issueZA = [&](int ec2, float4* zr) {      // 1 load / thread (uniform)
        const float* zsrc = (ec2 < 24) ? zr_b : zi_b;
        const int ch0 = (ec2 < 24 ? ec2 : ec2 - 24) * 32;
        int sl = tid & 255;
        int row = sl >> 3, qq = sl & 7;
        zr[0] = *(const float4*)(zsrc + (size_t)(th * 32 + row) * 768 + ch0 + qq * 4);
    };
    auto convertZA = [&](const float4* zr, char* buf) {
        int sl = tid & 255;
        int row = sl >> 3, qq = sl & 7;
        ushort4 pk;
        pk.x = f2bf(zr[0].x); pk.y = f2bf(zr[0].y);
        pk.z = f2bf(zr[0].z); pk.w = f2bf(zr[0].w);
        *(ushort4*)(buf + (qq >> 1) * 512 + row * 16 + (qq & 1) * 8) = pk;
    };

    v4f acc[2][4] = {};

    auto comp = [&](char* curA, char* curB) {
        v8bf a[2], bfv[4];
#pragma unroll
        for (int mi = 0; mi < 2; ++mi) a[mi] = *(const v8bf*)(curA + zaoff[mi]);
#pragma unroll
        for (int nj = 0; nj < 4; ++nj) bfv[nj] = *(const v8bf*)(curB + boff[nj]);
        __builtin_amdgcn_s_setprio(1);
#pragma unroll
        for (int mi = 0; mi < 2; ++mi)
#pragma unroll
            for (int nj = 0; nj < 4; ++nj)
                acc[mi][nj] = __builtin_amdgcn_mfma_f32_16x16x32_bf16(a[mi], bfv[nj], acc[mi][nj], 0, 0, 0);
        __builtin_amdgcn_s_setprio(0);
    };

    float4 zreg[1];
    {
        issueZA(0, zreg);
        stageZB(0, ldsZB);
        stageZB(1, ldsZB + ZB_BUF);
        convertZA(zreg, ldsZA);      // waits ZA(0)
        issueZA(1, zreg);
        BARRIER(5);                  // allow ZB(1)=4 + ZA(1)=1
    }
#pragma unroll 1
    for (int t = 0; t < 46; ++t) {
        stageZB(t + 2, ldsZB + ((t + 2) % 3) * ZB_BUF);
        comp(ldsZA + (t & 1) * ZA_BUF, ldsZB + (t % 3) * ZB_BUF);
        convertZA(zreg, ldsZA + ((t + 1) & 1) * ZA_BUF);  // waits ZA(t+1): vmcnt(4)
        issueZA(t + 2, zreg);
        BARRIER(5);                  // allow ZB(t+2)=4 + ZA(t+2)=1; drains ZB(t+1)
    }
    {   // t = 46
        comp(ldsZA + (46 & 1) * ZA_BUF, ldsZB + (46 % 3) * ZB_BUF);
        convertZA(zreg, ldsZA + (47 & 1) * ZA_BUF);       // waits ZA(47): vmcnt(0)
        BARRIER(0);
    }
    comp(ldsZA + (47 & 1) * ZA_BUF, ldsZB + (47 % 3) * ZB_BUF);

    // ---- bias + LN stats (rows 0..31 local) ----
    float fzb[4], lng[4], lnb[4];
#pragma unroll
    for (int nj = 0; nj < 4; ++nj) {
        int o = wid * 64 + nj * 16 + l15;
        fzb[nj] = fz_b[o]; lng[nj] = ln_g[o]; lnb[nj] = ln_b[o];
    }
#pragma unroll
    for (int mi = 0; mi < 2; ++mi)
#pragma unroll
        for (int nj = 0; nj < 4; ++nj)
#pragma unroll
            for (int reg = 0; reg < 4; ++reg)
                acc[mi][nj][reg] += fzb[nj];

#pragma unroll
    for (int mi = 0; mi < 2; ++mi) {
#pragma unroll
        for (int reg = 0; reg < 4; ++reg) {
            float s = 0.f, q = 0.f;
#pragma unroll
            for (int nj = 0; nj < 4; ++nj) {
                float v = acc[mi][nj][reg];
                s += v; q += v * v;
            }
#pragma unroll
            for (int m = 0; m < 4; ++m) {
                s += __shfl_xor(s, 1 << m, 64);
                q += __shfl_xor(q, 1 << m, 64);
            }
            if (l15 == 0) {
                int row = mi * 16 + h * 4 + reg;
                redS[wid * 32 + row] = s;
                redQ[wid * 32 + row] = q;
            }
        }
    }
    __syncthreads();
    if (tid < 32) {
        float s = 0.f, q = 0.f;
#pragma unroll
        for (int w6 = 0; w6 < 6; ++w6) { s += redS[w6 * 32 + tid]; q += redQ[w6 * 32 + tid]; }
        float mu = s * (1.0f / 384.0f);
        float var = q * (1.0f / 384.0f) - mu * mu;
        mu_s[tid] = mu;
        rs_s[tid] = rsqrtf(var + EPSF);
    }
    __syncthreads();

    // ---- LN + gelu -> zpk[b][o][t] ----
#pragma unroll
    for (int mi = 0; mi < 2; ++mi)
#pragma unroll
        for (int nj = 0; nj < 4; ++nj) {
            int o = wid * 64 + nj * 16 + l15;
            u32* dst = (u32*)zpk + ((size_t)b * 384 + o) * 32 + th * 16 + mi * 8 + h * 2;
#pragma unroll
            for (int rp = 0; rp < 2; ++rp) {
                float zv[2];
#pragma unroll
                for (int k = 0; k < 2; ++k) {
                    int reg = rp * 2 + k;
                    int row = mi * 16 + h * 4 + reg;
                    float v = (acc[mi][nj][reg] - mu_s[row]) * rs_s[row] * lng[nj] + lnb[nj];
                    zv[k] = gelu_exact(v);
                }
                dst[rp] = (u32)f2bf(zv[0]) | ((u32)f2bf(zv[1]) << 16);
            }
        }
}

// ---------------------------------------------------------------------------
// kc9: implicit-GEMM cropped conv. grid (6 = conv*3+nh, 128 b), 512 thr = 8 waves.
// M=64, N=128, K=6912 as 108 intervals x 2 taps (8 MFMA/wave/interval).
// B: 6-slot ring (stage interval g+2); A: double buffer per ec2 parity.
// LDS 72.2 KB -> 2 blocks/CU = 16 waves/CU. Counted-vmcnt ledger,
// 9-interval periodic barrier pattern. Bank-conflict-free pads.
// ---------------------------------------------------------------------------
#define APL9   2832            // A plane stride (176*16 + 16) -> h-planes 4-bank offset
#define ABUF9  (4 * APL9)      // 11328 per ec2 buffer
#define PBP9   2064            // B plane stride (128*16 + 16)
#define BSLOT9 (4 * PBP9)      // 8256 per tap slot

__global__ __launch_bounds__(512, 4) void kc9(const float* __restrict__ x_r,
                                              const float* __restrict__ x_i,
                                              const u16* __restrict__ Bw,
                                              const u16* __restrict__ zpk,
                                              const float* __restrict__ br,  const float* __restrict__ bnr_g,
                                              const float* __restrict__ bnr_b, const float* __restrict__ bnr_m,
                                              const float* __restrict__ bnr_v,
                                              const float* __restrict__ bi,  const float* __restrict__ bni_g,
                                              const float* __restrict__ bni_b, const float* __restrict__ bni_m,
                                              const float* __restrict__ bni_v,
                                              float* __restrict__ part) {
    const int q    = blockIdx.x;        // conv*3 + nh
    const int conv = q / 3;
    const int nh   = q % 3;
    const int b    = blockIdx.y;
    const int tid  = threadIdx.x;
    const int lane = tid & 63;
    const int wid  = tid >> 6;          // 0..7
    const int wm   = wid >> 2;          // 0..1 M-half
    const int wn   = wid & 3;           // 0..3 N-quarter
    const int l15  = lane & 15;
    const int h    = lane >> 4;         // 0..3

    __shared__ __align__(16) char ldsA[2 * ABUF9];    // 22656
    __shared__ __align__(16) char ldsB[6 * BSLOT9];   // 49536
    __shared__ float redF[8];

    const float* x  = conv ? x_i : x_r;
    const float* xb = x + (size_t)b * (256 * 768);

    int boff[2];
#pragma unroll
    for (int nj = 0; nj < 2; ++nj) {
        int nl = wn * 32 + nj * 16 + l15;
        boff[nj] = h * PBP9 + nl * 16;
    }
    int aoff[2];
#pragma unroll
    for (int mi = 0; mi < 2; ++mi) {
        int p = wm * 32 + mi * 16 + l15;
        int i = p >> 3, j = p & 7;
        aoff[mi] = h * APL9 + (i * 16 + j + 3) * 16;
    }

    auto stageB = [&](int T) {                        // 1 gload16 / thread
        int e2 = T / 9, s2 = T - e2 * 9;
        int hh = tid >> 7;
        int nl = tid & 127;
        const char* src = (const char*)Bw +
            (((size_t)conv * 864 + ((size_t)s2 * 24 + e2) * 4 + hh) * 384 + nh * 128 + nl) * 16;
        gload16(src, ldsB + (T % 6) * BSLOT9 + hh * PBP9 + nl * 16);
    };
    auto issueA = [&](int ec2, float4* ar) {          // 3 loads/thread (wrapped)
#pragma unroll
        for (int k = 0; k < 3; ++k) {
            int sl = tid + k * 512;
            if (sl >= 1408) sl -= 1408;
            int row = sl >> 3, qq = sl & 7;
            ar[k] = *(const float4*)(xb + (size_t)(48 + row) * 768 + ec2 * 32 + qq * 4);
        }
    };
    auto convertA = [&](const float4* ar, int ec2) {
        char* buf = ldsA + (ec2 & 1) * ABUF9;
#pragma unroll
        for (int k = 0; k < 3; ++k) {
            int sl = tid + k * 512;
            if (sl >= 1408) sl -= 1408;
            int row = sl >> 3, qq = sl & 7;
            ushort4 pk;
            pk.x = f2bf(ar[k].x); pk.y = f2bf(ar[k].y);
            pk.z = f2bf(ar[k].z); pk.w = f2bf(ar[k].w);
            *(ushort4*)(buf + (qq >> 1) * APL9 + row * 16 + (qq & 1) * 8) = pk;
        }
    };

    v4f acc[2][2] = {};

    auto comp = [&](int T) {
        int m9 = T % 9;
        int abase = ((T / 9) & 1) * ABUF9;
        int soff = ((m9 / 3) * 16 + (m9 % 3)) * 16;
        char* curB = ldsB + (T % 6) * BSLOT9;
        v8bf a[2], bfv[2];
#pragma unroll
        for (int mi = 0; mi < 2; ++mi) a[mi] = *(const v8bf*)(ldsA + abase + aoff[mi] + soff);
#pragma unroll
        for (int nj = 0; nj < 2; ++nj) bfv[nj] = *(const v8bf*)(curB + boff[nj]);
        __builtin_amdgcn_s_setprio(1);
#pragma unroll
        for (int mi = 0; mi < 2; ++mi)
#pragma unroll
            for (int nj = 0; nj < 2; ++nj)
                acc[mi][nj] = __builtin_amdgcn_mfma_f32_16x16x32_bf16(a[mi], bfv[nj], acc[mi][nj], 0, 0, 0);
        __builtin_amdgcn_s_setprio(0);
    };

    float4 areg[3];
    {   // prologue: A(0) first (oldest), B taps 0..3 behind it.
        issueA(0, areg);
        stageB(0); stageB(1); stageB(2); stageB(3);
        convertA(areg, 0);           // reg-dep waits areg
        BARRIER(2);                  // drain B(0),B(1); keep B(2),B(3)
    }

    // 11 uniform macro-blocks of 9 intervals (18 taps = 2 ec2), then tail.
    // m-pattern per macro-block: 0,2,4,6,8,1,3,5,7
#pragma unroll 1
    for (int blk = 0; blk < 11; ++blk) {
        const int t0 = blk * 18;
        const int e0 = blk * 2;
        // i0 (m0)
        stageB(t0 + 4);  stageB(t0 + 5);  issueA(e0 + 1, areg);
        comp(t0 + 0); comp(t0 + 1);  BARRIER(5);
        // i1 (m2)
        stageB(t0 + 6);  stageB(t0 + 7);
        comp(t0 + 2); comp(t0 + 3);  BARRIER(5);
        // i2 (m4)
        stageB(t0 + 8);  stageB(t0 + 9);
        comp(t0 + 4); comp(t0 + 5);  BARRIER(2);
        // i3 (m6) — convert A(e0+1)
        stageB(t0 + 10); stageB(t0 + 11);
        comp(t0 + 6); comp(t0 + 7);  BARRIER(2);
        convertA(areg, e0 + 1);      BARRIER(2);
        // i4 (m8) — issue A(e0+2)
        stageB(t0 + 12); stageB(t0 + 13); issueA(e0 + 2, areg);
        comp(t0 + 8); comp(t0 + 9);  BARRIER(5);
        // i5 (m1)
        stageB(t0 + 14); stageB(t0 + 15);
        comp(t0 + 10); comp(t0 + 11); BARRIER(5);
        // i6 (m3)
        stageB(t0 + 16); stageB(t0 + 17);
        comp(t0 + 12); comp(t0 + 13); BARRIER(2);
        // i7 (m5) — convert A(e0+2)
        stageB(t0 + 18); stageB(t0 + 19);
        comp(t0 + 14); comp(t0 + 15); BARRIER(2);
        convertA(areg, e0 + 2);      BARRIER(2);
        // i8 (m7)
        stageB(t0 + 20); stageB(t0 + 21);
        comp(t0 + 16); comp(t0 + 17); BARRIER(2);
    }
    {   // tail: taps 198..215 (ec2 22,23)
        stageB(202); stageB(203); issueA(23, areg);
        comp(198); comp(199); BARRIER(5);
        stageB(204); stageB(205);
        comp(200); comp(201); BARRIER(5);
        stageB(206); stageB(207);
        comp(202); comp(203); BARRIER(2);
        stageB(208); stageB(209);
        comp(204); comp(205); BARRIER(2);
        convertA(areg, 23);   BARRIER(2);
        stageB(210); stageB(211);
        comp(206); comp(207); BARRIER(2);
        stageB(212); stageB(213);
        comp(208); comp(209); BARRIER(2);
        stageB(214); stageB(215);
        comp(210); comp(211); BARRIER(2);
        comp(212); comp(213); BARRIER(0);
        comp(214); comp(215);
    }

    // ---- BN + gelu + dot(zpk) ----
    const float* bcp = conv ? bi    : br;
    const float* gp  = conv ? bni_g : bnr_g;
    const float* bbp = conv ? bni_b : bnr_b;
    const float* mp  = conv ? bni_m : bnr_m;
    const float* vp  = conv ? bni_v : bnr_v;

    float sum = 0.f;
#pragma unroll
    for (int nj = 0; nj < 2; ++nj) {
        const int o = nh * 128 + wn * 32 + nj * 16 + l15;
        const float sc = gp[o] * rsqrtf(vp[o] + EPSF);
        const float sh2 = (bcp[o] - mp[o]) * sc + bbp[o];
        const u16* zb = zpk + ((size_t)b * 384 + o) * 64;
#pragma unroll
        for (int mi = 0; mi < 2; ++mi) {
            ushort4 zw = *(const ushort4*)(zb + wm * 32 + mi * 16 + h * 4);
#pragma unroll
            for (int reg = 0; reg < 4; ++reg) {
                float y = fmaf(acc[mi][nj][reg], sc, sh2);
                u16 zu = (reg == 0) ? zw.x : (reg == 1) ? zw.y : (reg == 2) ? zw.z : zw.w;
                sum = fmaf(gelu_exact(y), bf2f(zu), sum);
            }
        }
    }
#pragma unroll
    for (int off = 32; off >= 1; off >>= 1) sum += __shfl_down(sum, off, 64);

    if (lane == 0) redF[wid] = sum;
    __syncthreads();
    if (tid == 0) {
        float t = 0.f;
#pragma unroll
        for (int w8 = 0; w8 < 8; ++w8) t += redF[w8];
        part[((size_t)conv * 128 + b) * 3 + nh] = t;
    }
}

// ---------------------------------------------------------------------------
// kr: combine n-third partials, sigmoid.
// ---------------------------------------------------------------------------
__global__ __launch_bounds__(256) void kr(const float* __restrict__ part,
                                          const float* __restrict__ c,
                                          float* __restrict__ out) {
    int v = threadIdx.x;     // 0..255 = conv*128+b
    float s = part[v * 3] + part[v * 3 + 1] + part[v * 3 + 2];
    out[v] = 1.f / (1.f + expf(-s / c[0]));
}

extern "C" void kernel_launch(void* const* d_in, const int* in_sizes, int n_in,
                              void* d_out, int out_size, void* d_ws, size_t ws_size,
                              hipStream_t stream) {
    const float* z_r   = (const float*)d_in[0];
    const float* z_i   = (const float*)d_in[1];
    const float* x_r   = (const float*)d_in[2];
    const float* x_i   = (const float*)d_in[3];
    const float* fz_w  = (const float*)d_in[4];
    const float* fz_b  = (const float*)d_in[5];
    const float* ln_g  = (const float*)d_in[6];
    const float* ln_b  = (const float*)d_in[7];
    const float* wr    = (const float*)d_in[8];
    const float* br    = (const float*)d_in[9];
    const float* bnr_g = (const float*)d_in[10];
    const float* bnr_b = (const float*)d_in[11];
    const float* bnr_m = (const float*)d_in[12];
    const float* bnr_v = (const float*)d_in[13];
    const float* wi    = (const float*)d_in[14];
    const float* bi    = (const float*)d_in[15];
    const float* bni_g = (const float*)d_in[16];
    const float* bni_b = (const float*)d_in[17];
    const float* bni_m = (const float*)d_in[18];
    const float* bni_v = (const float*)d_in[19];
    const float* c     = (const float*)d_in[20];

    // ws (bytes): Bz [0, 1179648) | Bw [+10616832) | zpk [+6291456) | part [+3072)
    u16*   Bz   = (u16*)d_ws;
    u16*   Bw   = (u16*)((char*)d_ws + 1179648);
    u16*   zpk  = (u16*)((char*)d_ws + 1179648 + 10616832);
    float* part = (float*)((char*)d_ws + 1179648 + 10616832 + 6291456);

    kprep_z<<<288, 256, 0, stream>>>(fz_w, Bz);
    kprep_w<<<768, 256, 0, stream>>>(wr, wi, Bw);
    kz2<<<dim3(2, 128), 384, 0, stream>>>(z_r, z_i, Bz, fz_b, ln_g, ln_b, zpk);
    kc9<<<dim3(6, 128), 512, 0, stream>>>(x_r, x_i, Bw, zpk,
                                          br, bnr_g, bnr_b, bnr_m, bnr_v,
                                          bi, bni_g, bni_b, bni_m, bni_v,
                                          part);
    kr<<<1, 256, 0, stream>>>(part, c, (float*)d_out);
}

// Round 13
// 187.693 us; speedup vs baseline: 1.7321x; 1.2905x over previous
//
#include <hip/hip_runtime.h>
#include <hip/hip_bf16.h>
#include <math.h>

#define EPSF 1e-5f

typedef __bf16 v8bf __attribute__((ext_vector_type(8)));
typedef float  v4f  __attribute__((ext_vector_type(4)));
typedef unsigned int u32;
typedef unsigned short u16;

__device__ __forceinline__ float gelu_exact(float x) {
    return 0.5f * x * (1.0f + erff(x * 0.70710678f));
}
__device__ __forceinline__ u16 f2bf(float f) {   // RNE
    u32 u = __float_as_uint(f);
    return (u16)((u + 0x7fffu + ((u >> 16) & 1u)) >> 16);
}
__device__ __forceinline__ float bf2f(u16 u) {
    return __uint_as_float(((u32)u) << 16);
}
__device__ __forceinline__ void gload16(const void* g, void* l) {
    __builtin_amdgcn_global_load_lds((const __attribute__((address_space(1))) u32*)g,
                                     (__attribute__((address_space(3))) u32*)l, 16, 0, 0);
}

// counted-vmcnt barrier: allow N vector-mem ops outstanding, drain LDS ops.
#define BARRIER(N) do { \
    asm volatile("s_waitcnt vmcnt(" #N ") lgkmcnt(0)" ::: "memory"); \
    __builtin_amdgcn_s_barrier(); \
} while (0)

// ---------------------------------------------------------------------------
// Prep: fz_w[o][1536] f32 -> Bz[ec2][h][n][8] bf16 (coalesced reads)
// ---------------------------------------------------------------------------
__global__ __launch_bounds__(256) void kprep_z(const float* __restrict__ fz_w,
                                               u16* __restrict__ Bz) {
    int idx = blockIdx.x * 256 + threadIdx.x;   // 0 .. 73727
    int n = idx / 192;
    int r = idx % 192;
    int ec2 = r >> 2;
    int h = r & 3;
    const float* src = fz_w + (size_t)n * 1536 + ec2 * 32 + h * 8;
    float4 v0 = *(const float4*)src;
    float4 v1 = *(const float4*)(src + 4);
    uint4 pk;
    pk.x = (u32)f2bf(v0.x) | ((u32)f2bf(v0.y) << 16);
    pk.y = (u32)f2bf(v0.z) | ((u32)f2bf(v0.w) << 16);
    pk.z = (u32)f2bf(v1.x) | ((u32)f2bf(v1.y) << 16);
    pk.w = (u32)f2bf(v1.z) | ((u32)f2bf(v1.w) << 16);
    size_t slot = ((size_t)(ec2 * 4 + h) * 384 + n);
    *(uint4*)(Bz + slot * 8) = pk;
}

// ---------------------------------------------------------------------------
// Prep: w[n][e][3][3] f32 -> Bw[conv][s][ec2][h][n][8] bf16.
// ---------------------------------------------------------------------------
__global__ __launch_bounds__(256) void kprep_w(const float* __restrict__ wr,
                                               const float* __restrict__ wi,
                                               u16* __restrict__ Bw) {
    __shared__ float wsm[6912];
    const int tid = threadIdx.x;
    const int n = blockIdx.x >> 1;
    const int conv = blockIdx.x & 1;
    const float* w = (conv ? wi : wr) + (size_t)n * 6912;
#pragma unroll
    for (int k = 0; k < 7; ++k) {
        int sl = tid + k * 256;
        if (sl < 1728) ((float4*)wsm)[sl] = ((const float4*)w)[sl];
    }
    __syncthreads();
#pragma unroll
    for (int k = 0; k < 4; ++k) {
        int sl = tid + k * 256;          // (s*24+ec2)*4 + h
        if (sl < 864) {
            int h = sl & 3;
            int r = sl >> 2;
            int ec2 = r % 24;
            int s = r / 24;
            int ch0 = ec2 * 32 + h * 8;
            u16 tmp[8];
#pragma unroll
            for (int e = 0; e < 8; ++e) tmp[e] = f2bf(wsm[(ch0 + e) * 9 + s]);
            uint4 pk;
            pk.x = (u32)tmp[0] | ((u32)tmp[1] << 16);
            pk.y = (u32)tmp[2] | ((u32)tmp[3] << 16);
            pk.z = (u32)tmp[4] | ((u32)tmp[5] << 16);
            pk.w = (u32)tmp[6] | ((u32)tmp[7] << 16);
            size_t slot = ((size_t)conv * 864 + sl) * 384 + n;
            *(uint4*)(Bw + slot * 8) = pk;
        }
    }
}

// ---------------------------------------------------------------------------
// kz2: z = gelu(LN(concat(z_r,z_i) @ fz_w^T + fz_b)) via MFMA.
// grid (2 t-halves, 128 b), 384 thr = 6 waves. Writes zpk[b][o][t(64)] bf16.
// ---------------------------------------------------------------------------
#define ZB_BUF 24576
#define ZA_BUF 2048

__global__ __launch_bounds__(384, 1) void kz2(const float* __restrict__ z_r,
                                              const float* __restrict__ z_i,
                                              const u16* __restrict__ Bz,
                                              const float* __restrict__ fz_b,
                                              const float* __restrict__ ln_g,
                                              const float* __restrict__ ln_b,
                                              u16* __restrict__ zpk) {
    const int th = blockIdx.x;
    const int b  = blockIdx.y;
    const int tid  = threadIdx.x;
    const int lane = tid & 63;
    const int wid  = tid >> 6;
    const int l15  = lane & 15;
    const int h    = lane >> 4;

    __shared__ __align__(16) char lds[3 * ZB_BUF + 2 * ZA_BUF];   // 77824
    char* ldsZB = lds;
    char* ldsZA = lds + 3 * ZB_BUF;
    __shared__ float redS[6 * 32], redQ[6 * 32], mu_s[32], rs_s[32];

    const float* zr_b = z_r + (size_t)b * (64 * 768);
    const float* zi_b = z_i + (size_t)b * (64 * 768);

    int boff[4];
#pragma unroll
    for (int nj = 0; nj < 4; ++nj) {
        int n = wid * 64 + nj * 16 + l15;
        boff[nj] = h * 6144 + n * 16;
    }
    int zaoff[2];
#pragma unroll
    for (int mi = 0; mi < 2; ++mi)
        zaoff[mi] = h * 512 + (mi * 16 + l15) * 16;

    auto stageZB = [&](int ec2, char* buf) {       // 4 gload16 / thread
        const char* src = (const char*)(Bz + (size_t)ec2 * 1536 * 8);
#pragma unroll
        for (int k = 0; k < 4; ++k) {
            int sl = tid + k * 384;
            gload16(src + sl * 16, buf + sl * 16);
        }
    };
    auto issueZA = [&](int ec2, float4* zr) {      // 1 load / thread (uniform)
        const float* zsrc = (ec2 < 24) ? zr_b : zi_b;
        const int ch0 = (ec2 < 24 ? ec2 : ec2 - 24) * 32;
        int sl = tid & 255;
        int row = sl >> 3, qq = sl & 7;
        zr[0] = *(const float4*)(zsrc + (size_t)(th * 32 + row) * 768 + ch0 + qq * 4);
    };
    auto convertZA = [&](const float4* zr, char* buf) {
        int sl = tid & 255;
        int row = sl >> 3, qq = sl & 7;
        ushort4 pk;
        pk.x = f2bf(zr[0].x); pk.y = f2bf(zr[0].y);
        pk.z = f2bf(zr[0].z); pk.w = f2bf(zr[0].w);
        *(ushort4*)(buf + (qq >> 1) * 512 + row * 16 + (qq & 1) * 8) = pk;
    };

    v4f acc[2][4] = {};

    auto comp = [&](char* curA, char* curB) {
        v8bf a[2], bfv[4];
#pragma unroll
        for (int mi = 0; mi < 2; ++mi) a[mi] = *(const v8bf*)(curA + zaoff[mi]);
#pragma unroll
        for (int nj = 0; nj < 4; ++nj) bfv[nj] = *(const v8bf*)(curB + boff[nj]);
        __builtin_amdgcn_s_setprio(1);
#pragma unroll
        for (int mi = 0; mi < 2; ++mi)
#pragma unroll
            for (int nj = 0; nj < 4; ++nj)
                acc[mi][nj] = __builtin_amdgcn_mfma_f32_16x16x32_bf16(a[mi], bfv[nj], acc[mi][nj], 0, 0, 0);
        __builtin_amdgcn_s_setprio(0);
    };

    float4 zreg[1];
    {
        issueZA(0, zreg);
        stageZB(0, ldsZB);
        stageZB(1, ldsZB + ZB_BUF);
        convertZA(zreg, ldsZA);      // waits ZA(0)
        issueZA(1, zreg);
        BARRIER(5);                  // allow ZB(1)=4 + ZA(1)=1
    }
#pragma unroll 1
    for (int t = 0; t < 46; ++t) {
        stageZB(t + 2, ldsZB + ((t + 2) % 3) * ZB_BUF);
        comp(ldsZA + (t & 1) * ZA_BUF, ldsZB + (t % 3) * ZB_BUF);
        convertZA(zreg, ldsZA + ((t + 1) & 1) * ZA_BUF);  // waits ZA(t+1): vmcnt(4)
        issueZA(t + 2, zreg);
        BARRIER(5);                  // allow ZB(t+2)=4 + ZA(t+2)=1; drains ZB(t+1)
    }
    {   // t = 46
        comp(ldsZA + (46 & 1) * ZA_BUF, ldsZB + (46 % 3) * ZB_BUF);
        convertZA(zreg, ldsZA + (47 & 1) * ZA_BUF);       // waits ZA(47): vmcnt(0)
        BARRIER(0);
    }
    comp(ldsZA + (47 & 1) * ZA_BUF, ldsZB + (47 % 3) * ZB_BUF);

    // ---- bias + LN stats (rows 0..31 local) ----
    float fzb[4], lng[4], lnb[4];
#pragma unroll
    for (int nj = 0; nj < 4; ++nj) {
        int o = wid * 64 + nj * 16 + l15;
        fzb[nj] = fz_b[o]; lng[nj] = ln_g[o]; lnb[nj] = ln_b[o];
    }
#pragma unroll
    for (int mi = 0; mi < 2; ++mi)
#pragma unroll
        for (int nj = 0; nj < 4; ++nj)
#pragma unroll
            for (int reg = 0; reg < 4; ++reg)
                acc[mi][nj][reg] += fzb[nj];

#pragma unroll
    for (int mi = 0; mi < 2; ++mi) {
#pragma unroll
        for (int reg = 0; reg < 4; ++reg) {
            float s = 0.f, q = 0.f;
#pragma unroll
            for (int nj = 0; nj < 4; ++nj) {
                float v = acc[mi][nj][reg];
                s += v; q += v * v;
            }
#pragma unroll
            for (int m = 0; m < 4; ++m) {
                s += __shfl_xor(s, 1 << m, 64);
                q += __shfl_xor(q, 1 << m, 64);
            }
            if (l15 == 0) {
                int row = mi * 16 + h * 4 + reg;
                redS[wid * 32 + row] = s;
                redQ[wid * 32 + row] = q;
            }
        }
    }
    __syncthreads();
    if (tid < 32) {
        float s = 0.f, q = 0.f;
#pragma unroll
        for (int w6 = 0; w6 < 6; ++w6) { s += redS[w6 * 32 + tid]; q += redQ[w6 * 32 + tid]; }
        float mu = s * (1.0f / 384.0f);
        float var = q * (1.0f / 384.0f) - mu * mu;
        mu_s[tid] = mu;
        rs_s[tid] = rsqrtf(var + EPSF);
    }
    __syncthreads();

    // ---- LN + gelu -> zpk[b][o][t] ----
#pragma unroll
    for (int mi = 0; mi < 2; ++mi)
#pragma unroll
        for (int nj = 0; nj < 4; ++nj) {
            int o = wid * 64 + nj * 16 + l15;
            u32* dst = (u32*)zpk + ((size_t)b * 384 + o) * 32 + th * 16 + mi * 8 + h * 2;
#pragma unroll
            for (int rp = 0; rp < 2; ++rp) {
                float zv[2];
#pragma unroll
                for (int k = 0; k < 2; ++k) {
                    int reg = rp * 2 + k;
                    int row = mi * 16 + h * 4 + reg;
                    float v = (acc[mi][nj][reg] - mu_s[row]) * rs_s[row] * lng[nj] + lnb[nj];
                    zv[k] = gelu_exact(v);
                }
                dst[rp] = (u32)f2bf(zv[0]) | ((u32)f2bf(zv[1]) << 16);
            }
        }
}

// ---------------------------------------------------------------------------
// kc10: implicit-GEMM cropped conv; B fragments loaded straight from global
// into registers (3-tap prefetch); LDS holds only A (double buffer).
// grid (6 = conv*3+nh, 128 b), 512 thr = 8 waves, wave tile 64x16 (4 MFMA/tap).
// ONE barrier per ec2 (24 total); 36 MFMA/wave per barrier.
// LDS 22.9 KB; __launch_bounds__(512,4) -> VGPR<=128 -> 2 blocks/CU.
// ---------------------------------------------------------------------------
#define APL10  2848            // A h-plane stride (176*16 + 32)
#define ABUF10 (4 * APL10)     // 11392 per ec2 buffer

__global__ __launch_bounds__(512, 4) void kc10(const float* __restrict__ x_r,
                                               const float* __restrict__ x_i,
                                               const u16* __restrict__ Bw,
                                               const u16* __restrict__ zpk,
                                               const float* __restrict__ br,  const float* __restrict__ bnr_g,
                                               const float* __restrict__ bnr_b, const float* __restrict__ bnr_m,
                                               const float* __restrict__ bnr_v,
                                               const float* __restrict__ bi,  const float* __restrict__ bni_g,
                                               const float* __restrict__ bni_b, const float* __restrict__ bni_m,
                                               const float* __restrict__ bni_v,
                                               float* __restrict__ part) {
    const int q    = blockIdx.x;        // conv*3 + nh
    const int conv = q / 3;
    const int nh   = q % 3;
    const int b    = blockIdx.y;
    const int tid  = threadIdx.x;
    const int lane = tid & 63;
    const int wid  = tid >> 6;          // 0..7 = 16-col group
    const int l15  = lane & 15;
    const int h    = lane >> 4;         // 0..3

    __shared__ __align__(16) char ldsA[2 * ABUF10];   // 22784
    __shared__ float redF[8];

    const float* x  = conv ? x_i : x_r;
    const float* xb = x + (size_t)b * (256 * 768);

    // B fragment base: this thread's fixed (h, col) within a tap slab.
    const char* bbase = (const char*)(Bw + (size_t)conv * (864 * 384 * 8))
                      + (size_t)h * 6144 + (nh * 128 + wid * 16 + l15) * 16;

    int aoff[4];
#pragma unroll
    for (int mi = 0; mi < 4; ++mi) {
        int p = mi * 16 + l15;
        int i = p >> 3, j = p & 7;
        aoff[mi] = h * APL10 + (i * 16 + j + 3) * 16;
    }

    auto issueA = [&](int ec2, float4* ar) {          // 3 loads/thread (wrapped)
#pragma unroll
        for (int k = 0; k < 3; ++k) {
            int sl = tid + k * 512;
            if (sl >= 1408) sl -= 1408;
            int row = sl >> 3, qq = sl & 7;
            ar[k] = *(const float4*)(xb + (size_t)(48 + row) * 768 + ec2 * 32 + qq * 4);
        }
    };
    auto convertA = [&](const float4* ar, char* buf) {
#pragma unroll
        for (int k = 0; k < 3; ++k) {
            int sl = tid + k * 512;
            if (sl >= 1408) sl -= 1408;
            int row = sl >> 3, qq = sl & 7;
            ushort4 pk;
            pk.x = f2bf(ar[k].x); pk.y = f2bf(ar[k].y);
            pk.z = f2bf(ar[k].z); pk.w = f2bf(ar[k].w);
            *(ushort4*)(buf + (qq >> 1) * APL10 + row * 16 + (qq & 1) * 8) = pk;
        }
    };

    v4f acc[4] = {};
    v8bf bpipe[3];
    float4 areg[3];

    {   // prologue
        issueA(0, areg);
        bpipe[0] = *(const v8bf*)(bbase + (size_t)(0 * 24) * 24576);   // B(e=0,s=0)
        bpipe[1] = *(const v8bf*)(bbase + (size_t)(1 * 24) * 24576);   // B(0,1)
        bpipe[2] = *(const v8bf*)(bbase + (size_t)(2 * 24) * 24576);   // B(0,2)
        convertA(areg, ldsA);        // reg-dep waits areg; bpipe stays in flight
        __syncthreads();
    }

    // TAP(S): compute tap (e, S); prefetch B 3 taps ahead into bpipe[S%3].
#define TAP(S) do { \
        v8bf bu = bpipe[(S) % 3]; \
        v8bf a0 = *(const v8bf*)(Acur + aoff[0] + ((((S) / 3) * 16 + ((S) % 3)) * 16)); \
        v8bf a1 = *(const v8bf*)(Acur + aoff[1] + ((((S) / 3) * 16 + ((S) % 3)) * 16)); \
        v8bf a2 = *(const v8bf*)(Acur + aoff[2] + ((((S) / 3) * 16 + ((S) % 3)) * 16)); \
        v8bf a3 = *(const v8bf*)(Acur + aoff[3] + ((((S) / 3) * 16 + ((S) % 3)) * 16)); \
        __builtin_amdgcn_s_setprio(1); \
        acc[0] = __builtin_amdgcn_mfma_f32_16x16x32_bf16(a0, bu, acc[0], 0, 0, 0); \
        acc[1] = __builtin_amdgcn_mfma_f32_16x16x32_bf16(a1, bu, acc[1], 0, 0, 0); \
        acc[2] = __builtin_amdgcn_mfma_f32_16x16x32_bf16(a2, bu, acc[2], 0, 0, 0); \
        acc[3] = __builtin_amdgcn_mfma_f32_16x16x32_bf16(a3, bu, acc[3], 0, 0, 0); \
        __builtin_amdgcn_s_setprio(0); \
        if ((S) <= 5) { \
            bpipe[(S) % 3] = *(const v8bf*)(bptr + (size_t)(((S) + 3) * 24) * 24576); \
        } else if (e < 23) { \
            bpipe[(S) % 3] = *(const v8bf*)(bptr + (size_t)((((S) - 6) * 24) + 1) * 24576); \
        } \
    } while (0)

#pragma unroll 1
    for (int e = 0; e < 24; ++e) {
        const char* Acur = ldsA + (e & 1) * ABUF10;
        const char* bptr = bbase + (size_t)e * 24576;
        TAP(0); TAP(1); TAP(2);
        if (e < 23) issueA(e + 1, areg);
        TAP(3); TAP(4); TAP(5); TAP(6);
        if (e < 23) convertA(areg, ldsA + ((e + 1) & 1) * ABUF10);
        TAP(7); TAP(8);
        __syncthreads();
    }
#undef TAP

    // ---- BN + gelu + dot(zpk) ----
    const float* bcp = conv ? bi    : br;
    const float* gp  = conv ? bni_g : bnr_g;
    const float* bbp = conv ? bni_b : bnr_b;
    const float* mp  = conv ? bni_m : bnr_m;
    const float* vp  = conv ? bni_v : bnr_v;

    const int o = nh * 128 + wid * 16 + l15;
    const float sc  = gp[o] * rsqrtf(vp[o] + EPSF);
    const float sh2 = (bcp[o] - mp[o]) * sc + bbp[o];
    const u16* zb = zpk + ((size_t)b * 384 + o) * 64;

    float sum = 0.f;
#pragma unroll
    for (int mi = 0; mi < 4; ++mi) {
        ushort4 zw = *(const ushort4*)(zb + mi * 16 + h * 4);
#pragma unroll
        for (int reg = 0; reg < 4; ++reg) {
            float y = fmaf(acc[mi][reg], sc, sh2);
            u16 zu = (reg == 0) ? zw.x : (reg == 1) ? zw.y : (reg == 2) ? zw.z : zw.w;
            sum = fmaf(gelu_exact(y), bf2f(zu), sum);
        }
    }
#pragma unroll
    for (int off = 32; off >= 1; off >>= 1) sum += __shfl_down(sum, off, 64);

    if (lane == 0) redF[wid] = sum;
    __syncthreads();
    if (tid == 0) {
        float t = 0.f;
#pragma unroll
        for (int w8 = 0; w8 < 8; ++w8) t += redF[w8];
        part[((size_t)conv * 128 + b) * 3 + nh] = t;
    }
}

// ---------------------------------------------------------------------------
// kr: combine n-third partials, sigmoid.
// ---------------------------------------------------------------------------
__global__ __launch_bounds__(256) void kr(const float* __restrict__ part,
                                          const float* __restrict__ c,
                                          float* __restrict__ out) {
    int v = threadIdx.x;     // 0..255 = conv*128+b
    float s = part[v * 3] + part[v * 3 + 1] + part[v * 3 + 2];
    out[v] = 1.f / (1.f + expf(-s / c[0]));
}

extern "C" void kernel_launch(void* const* d_in, const int* in_sizes, int n_in,
                              void* d_out, int out_size, void* d_ws, size_t ws_size,
                              hipStream_t stream) {
    const float* z_r   = (const float*)d_in[0];
    const float* z_i   = (const float*)d_in[1];
    const float* x_r   = (const float*)d_in[2];
    const float* x_i   = (const float*)d_in[3];
    const float* fz_w  = (const float*)d_in[4];
    const float* fz_b  = (const float*)d_in[5];
    const float* ln_g  = (const float*)d_in[6];
    const float* ln_b  = (const float*)d_in[7];
    const float* wr    = (const float*)d_in[8];
    const float* br    = (const float*)d_in[9];
    const float* bnr_g = (const float*)d_in[10];
    const float* bnr_b = (const float*)d_in[11];
    const float* bnr_m = (const float*)d_in[12];
    const float* bnr_v = (const float*)d_in[13];
    const float* wi    = (const float*)d_in[14];
    const float* bi    = (const float*)d_in[15];
    const float* bni_g = (const float*)d_in[16];
    const float* bni_b = (const float*)d_in[17];
    const float* bni_m = (const float*)d_in[18];
    const float* bni_v = (const float*)d_in[19];
    const float* c     = (const float*)d_in[20];

    // ws (bytes): Bz [0, 1179648) | Bw [+10616832) | zpk [+6291456) | part [+3072)
    u16*   Bz   = (u16*)d_ws;
    u16*   Bw   = (u16*)((char*)d_ws + 1179648);
    u16*   zpk  = (u16*)((char*)d_ws + 1179648 + 10616832);
    float* part = (float*)((char*)d_ws + 1179648 + 10616832 + 6291456);

    kprep_z<<<288, 256, 0, stream>>>(fz_w, Bz);
    kprep_w<<<768, 256, 0, stream>>>(wr, wi, Bw);
    kz2<<<dim3(2, 128), 384, 0, stream>>>(z_r, z_i, Bz, fz_b, ln_g, ln_b, zpk);
    kc10<<<dim3(6, 128), 512, 0, stream>>>(x_r, x_i, Bw, zpk,
                                           br, bnr_g, bnr_b, bnr_m, bnr_v,
                                           bi, bni_g, bni_b, bni_m, bni_v,
                                           part);
    kr<<<1, 256, 0, stream>>>(part, c, (float*)d_out);
}

// Round 14
// 182.347 us; speedup vs baseline: 1.7828x; 1.0293x over previous
//
#include <hip/hip_runtime.h>
#include <hip/hip_bf16.h>
#include <math.h>

#define EPSF 1e-5f

typedef __bf16 v8bf __attribute__((ext_vector_type(8)));
typedef float  v4f  __attribute__((ext_vector_type(4)));
typedef unsigned int u32;
typedef unsigned short u16;

__device__ __forceinline__ float gelu_exact(float x) {
    return 0.5f * x * (1.0f + erff(x * 0.70710678f));
}
__device__ __forceinline__ u16 f2bf(float f) {   // RNE
    u32 u = __float_as_uint(f);
    return (u16)((u + 0x7fffu + ((u >> 16) & 1u)) >> 16);
}
__device__ __forceinline__ float bf2f(u16 u) {
    return __uint_as_float(((u32)u) << 16);
}
__device__ __forceinline__ void gload16(const void* g, void* l) {
    __builtin_amdgcn_global_load_lds((const __attribute__((address_space(1))) u32*)g,
                                     (__attribute__((address_space(3))) u32*)l, 16, 0, 0);
}

// counted-vmcnt barrier: allow N vector-mem ops outstanding, drain LDS ops.
#define BARRIER(N) do { \
    asm volatile("s_waitcnt vmcnt(" #N ") lgkmcnt(0)" ::: "memory"); \
    __builtin_amdgcn_s_barrier(); \
} while (0)

// ---------------------------------------------------------------------------
// Prep: fz_w[o][1536] f32 -> Bz[ec2][h][n][8] bf16 (coalesced reads)
// ---------------------------------------------------------------------------
__global__ __launch_bounds__(256) void kprep_z(const float* __restrict__ fz_w,
                                               u16* __restrict__ Bz) {
    int idx = blockIdx.x * 256 + threadIdx.x;   // 0 .. 73727
    int n = idx / 192;
    int r = idx % 192;
    int ec2 = r >> 2;
    int h = r & 3;
    const float* src = fz_w + (size_t)n * 1536 + ec2 * 32 + h * 8;
    float4 v0 = *(const float4*)src;
    float4 v1 = *(const float4*)(src + 4);
    uint4 pk;
    pk.x = (u32)f2bf(v0.x) | ((u32)f2bf(v0.y) << 16);
    pk.y = (u32)f2bf(v0.z) | ((u32)f2bf(v0.w) << 16);
    pk.z = (u32)f2bf(v1.x) | ((u32)f2bf(v1.y) << 16);
    pk.w = (u32)f2bf(v1.z) | ((u32)f2bf(v1.w) << 16);
    size_t slot = ((size_t)(ec2 * 4 + h) * 384 + n);
    *(uint4*)(Bz + slot * 8) = pk;
}

// ---------------------------------------------------------------------------
// Prep: w[n][e][3][3] f32 -> Bw[conv][s][ec2][h][n][8] bf16.
// ---------------------------------------------------------------------------
__global__ __launch_bounds__(256) void kprep_w(const float* __restrict__ wr,
                                               const float* __restrict__ wi,
                                               u16* __restrict__ Bw) {
    __shared__ float wsm[6912];
    const int tid = threadIdx.x;
    const int n = blockIdx.x >> 1;
    const int conv = blockIdx.x & 1;
    const float* w = (conv ? wi : wr) + (size_t)n * 6912;
#pragma unroll
    for (int k = 0; k < 7; ++k) {
        int sl = tid + k * 256;
        if (sl < 1728) ((float4*)wsm)[sl] = ((const float4*)w)[sl];
    }
    __syncthreads();
#pragma unroll
    for (int k = 0; k < 4; ++k) {
        int sl = tid + k * 256;          // (s*24+ec2)*4 + h
        if (sl < 864) {
            int h = sl & 3;
            int r = sl >> 2;
            int ec2 = r % 24;
            int s = r / 24;
            int ch0 = ec2 * 32 + h * 8;
            u16 tmp[8];
#pragma unroll
            for (int e = 0; e < 8; ++e) tmp[e] = f2bf(wsm[(ch0 + e) * 9 + s]);
            uint4 pk;
            pk.x = (u32)tmp[0] | ((u32)tmp[1] << 16);
            pk.y = (u32)tmp[2] | ((u32)tmp[3] << 16);
            pk.z = (u32)tmp[4] | ((u32)tmp[5] << 16);
            pk.w = (u32)tmp[6] | ((u32)tmp[7] << 16);
            size_t slot = ((size_t)conv * 864 + sl) * 384 + n;
            *(uint4*)(Bw + slot * 8) = pk;
        }
    }
}

// ---------------------------------------------------------------------------
// kz2: z = gelu(LN(concat(z_r,z_i) @ fz_w^T + fz_b)) via MFMA.
// grid (2 t-halves, 128 b), 384 thr = 6 waves. Writes zpk[b][o][t(64)] bf16.
// ---------------------------------------------------------------------------
#define ZB_BUF 24576
#define ZA_BUF 2048

__global__ __launch_bounds__(384, 1) void kz2(const float* __restrict__ z_r,
                                              const float* __restrict__ z_i,
                                              const u16* __restrict__ Bz,
                                              const float* __restrict__ fz_b,
                                              const float* __restrict__ ln_g,
                                              const float* __restrict__ ln_b,
                                              u16* __restrict__ zpk) {
    const int th = blockIdx.x;
    const int b  = blockIdx.y;
    const int tid  = threadIdx.x;
    const int lane = tid & 63;
    const int wid  = tid >> 6;
    const int l15  = lane & 15;
    const int h    = lane >> 4;

    __shared__ __align__(16) char lds[3 * ZB_BUF + 2 * ZA_BUF];   // 77824
    char* ldsZB = lds;
    char* ldsZA = lds + 3 * ZB_BUF;
    __shared__ float redS[6 * 32], redQ[6 * 32], mu_s[32], rs_s[32];

    const float* zr_b = z_r + (size_t)b * (64 * 768);
    const float* zi_b = z_i + (size_t)b * (64 * 768);

    int boff[4];
#pragma unroll
    for (int nj = 0; nj < 4; ++nj) {
        int n = wid * 64 + nj * 16 + l15;
        boff[nj] = h * 6144 + n * 16;
    }
    int zaoff[2];
#pragma unroll
    for (int mi = 0; mi < 2; ++mi)
        zaoff[mi] = h * 512 + (mi * 16 + l15) * 16;

    auto stageZB = [&](int ec2, char* buf) {       // 4 gload16 / thread
        const char* src = (const char*)(Bz + (size_t)ec2 * 1536 * 8);
#pragma unroll
        for (int k = 0; k < 4; ++k) {
            int sl = tid + k * 384;
            gload16(src + sl * 16, buf + sl * 16);
        }
    };
    auto issueZA = [&](int ec2, float4* zr) {      // 1 load / thread (uniform)
        const float* zsrc = (ec2 < 24) ? zr_b : zi_b;
        const int ch0 = (ec2 < 24 ? ec2 : ec2 - 24) * 32;
        int sl = tid & 255;
        int row = sl >> 3, qq = sl & 7;
        zr[0] = *(const float4*)(zsrc + (size_t)(th * 32 + row) * 768 + ch0 + qq * 4);
    };
    auto convertZA = [&](const float4* zr, char* buf) {
        int sl = tid & 255;
        int row = sl >> 3, qq = sl & 7;
        ushort4 pk;
        pk.x = f2bf(zr[0].x); pk.y = f2bf(zr[0].y);
        pk.z = f2bf(zr[0].z); pk.w = f2bf(zr[0].w);
        *(ushort4*)(buf + (qq >> 1) * 512 + row * 16 + (qq & 1) * 8) = pk;
    };

    v4f acc[2][4] = {};

    auto comp = [&](char* curA, char* curB) {
        v8bf a[2], bfv[4];
#pragma unroll
        for (int mi = 0; mi < 2; ++mi) a[mi] = *(const v8bf*)(curA + zaoff[mi]);
#pragma unroll
        for (int nj = 0; nj < 4; ++nj) bfv[nj] = *(const v8bf*)(curB + boff[nj]);
        __builtin_amdgcn_s_setprio(1);
#pragma unroll
        for (int mi = 0; mi < 2; ++mi)
#pragma unroll
            for (int nj = 0; nj < 4; ++nj)
                acc[mi][nj] = __builtin_amdgcn_mfma_f32_16x16x32_bf16(a[mi], bfv[nj], acc[mi][nj], 0, 0, 0);
        __builtin_amdgcn_s_setprio(0);
    };

    float4 zreg[1];
    {
        issueZA(0, zreg);
        stageZB(0, ldsZB);
        stageZB(1, ldsZB + ZB_BUF);
        convertZA(zreg, ldsZA);      // waits ZA(0)
        issueZA(1, zreg);
        BARRIER(5);                  // allow ZB(1)=4 + ZA(1)=1
    }
#pragma unroll 1
    for (int t = 0; t < 46; ++t) {
        stageZB(t + 2, ldsZB + ((t + 2) % 3) * ZB_BUF);
        comp(ldsZA + (t & 1) * ZA_BUF, ldsZB + (t % 3) * ZB_BUF);
        convertZA(zreg, ldsZA + ((t + 1) & 1) * ZA_BUF);  // waits ZA(t+1): vmcnt(4)
        issueZA(t + 2, zreg);
        BARRIER(5);                  // allow ZB(t+2)=4 + ZA(t+2)=1; drains ZB(t+1)
    }
    {   // t = 46
        comp(ldsZA + (46 & 1) * ZA_BUF, ldsZB + (46 % 3) * ZB_BUF);
        convertZA(zreg, ldsZA + (47 & 1) * ZA_BUF);       // waits ZA(47): vmcnt(0)
        BARRIER(0);
    }
    comp(ldsZA + (47 & 1) * ZA_BUF, ldsZB + (47 % 3) * ZB_BUF);

    // ---- bias + LN stats (rows 0..31 local) ----
    float fzb[4], lng[4], lnb[4];
#pragma unroll
    for (int nj = 0; nj < 4; ++nj) {
        int o = wid * 64 + nj * 16 + l15;
        fzb[nj] = fz_b[o]; lng[nj] = ln_g[o]; lnb[nj] = ln_b[o];
    }
#pragma unroll
    for (int mi = 0; mi < 2; ++mi)
#pragma unroll
        for (int nj = 0; nj < 4; ++nj)
#pragma unroll
            for (int reg = 0; reg < 4; ++reg)
                acc[mi][nj][reg] += fzb[nj];

#pragma unroll
    for (int mi = 0; mi < 2; ++mi) {
#pragma unroll
        for (int reg = 0; reg < 4; ++reg) {
            float s = 0.f, q = 0.f;
#pragma unroll
            for (int nj = 0; nj < 4; ++nj) {
                float v = acc[mi][nj][reg];
                s += v; q += v * v;
            }
#pragma unroll
            for (int m = 0; m < 4; ++m) {
                s += __shfl_xor(s, 1 << m, 64);
                q += __shfl_xor(q, 1 << m, 64);
            }
            if (l15 == 0) {
                int row = mi * 16 + h * 4 + reg;
                redS[wid * 32 + row] = s;
                redQ[wid * 32 + row] = q;
            }
        }
    }
    __syncthreads();
    if (tid < 32) {
        float s = 0.f, q = 0.f;
#pragma unroll
        for (int w6 = 0; w6 < 6; ++w6) { s += redS[w6 * 32 + tid]; q += redQ[w6 * 32 + tid]; }
        float mu = s * (1.0f / 384.0f);
        float var = q * (1.0f / 384.0f) - mu * mu;
        mu_s[tid] = mu;
        rs_s[tid] = rsqrtf(var + EPSF);
    }
    __syncthreads();

    // ---- LN + gelu -> zpk[b][o][t] ----
#pragma unroll
    for (int mi = 0; mi < 2; ++mi)
#pragma unroll
        for (int nj = 0; nj < 4; ++nj) {
            int o = wid * 64 + nj * 16 + l15;
            u32* dst = (u32*)zpk + ((size_t)b * 384 + o) * 32 + th * 16 + mi * 8 + h * 2;
#pragma unroll
            for (int rp = 0; rp < 2; ++rp) {
                float zv[2];
#pragma unroll
                for (int k = 0; k < 2; ++k) {
                    int reg = rp * 2 + k;
                    int row = mi * 16 + h * 4 + reg;
                    float v = (acc[mi][nj][reg] - mu_s[row]) * rs_s[row] * lng[nj] + lnb[nj];
                    zv[k] = gelu_exact(v);
                }
                dst[rp] = (u32)f2bf(zv[0]) | ((u32)f2bf(zv[1]) << 16);
            }
        }
}

// ---------------------------------------------------------------------------
// kc11: implicit-GEMM cropped conv; B in registers (6-tap-deep prefetch),
// LDS holds only A (double buffer). Wave tile 64x32 (8 MFMA : 4 ds_read).
// grid (4 = conv*2+nh, 128 b) = 512 blocks = 2/CU, 384 thr = 6 waves.
// One counted barrier per ec2 (24 total, 12 B-loads stay in flight).
// ---------------------------------------------------------------------------
#define APL11  2848            // A h-plane stride (176*16 + 32)
#define ABUF11 (4 * APL11)     // 11392 per ec2 buffer
#define SSTRIDE 589824         // 24 * 24576 : tap-s stride in Bw
#define ESTRIDE 24576          // ec2 stride in Bw

__global__ __launch_bounds__(384, 3) void kc11(const float* __restrict__ x_r,
                                               const float* __restrict__ x_i,
                                               const u16* __restrict__ Bw,
                                               const u16* __restrict__ zpk,
                                               const float* __restrict__ br,  const float* __restrict__ bnr_g,
                                               const float* __restrict__ bnr_b, const float* __restrict__ bnr_m,
                                               const float* __restrict__ bnr_v,
                                               const float* __restrict__ bi,  const float* __restrict__ bni_g,
                                               const float* __restrict__ bni_b, const float* __restrict__ bni_m,
                                               const float* __restrict__ bni_v,
                                               float* __restrict__ part) {
    const int q    = blockIdx.x;        // conv*2 + nh
    const int conv = q >> 1;
    const int nh   = q & 1;
    const int b    = blockIdx.y;
    const int tid  = threadIdx.x;
    const int lane = tid & 63;
    const int wid  = tid >> 6;          // 0..5 = 32-col group
    const int l15  = lane & 15;
    const int h    = lane >> 4;         // 0..3

    __shared__ __align__(16) char ldsA[2 * ABUF11];   // 22784
    __shared__ float redF[6];

    const float* x  = conv ? x_i : x_r;
    const float* xb = x + (size_t)b * (256 * 768);

    // B fragment base: this thread's (h, col0) within a tap slab.
    const char* bbase = (const char*)(Bw + (size_t)conv * (864 * 384 * 8))
                      + (size_t)h * 6144 + (nh * 192 + wid * 32 + l15) * 16;

    int aoff[4];
#pragma unroll
    for (int mi = 0; mi < 4; ++mi) {
        int p = mi * 16 + l15;
        int i = p >> 3, j = p & 7;
        aoff[mi] = h * APL11 + (i * 16 + j + 3) * 16;
    }

    auto issueA = [&](int ec2, float4* ar) {          // 4 loads/thread (wrapped)
#pragma unroll
        for (int k = 0; k < 4; ++k) {
            int sl = tid + k * 384;
            if (sl >= 1408) sl -= 1408;
            int row = sl >> 3, qq = sl & 7;
            ar[k] = *(const float4*)(xb + (size_t)(48 + row) * 768 + ec2 * 32 + qq * 4);
        }
    };
    auto convertA = [&](const float4* ar, char* buf) {
#pragma unroll
        for (int k = 0; k < 4; ++k) {
            int sl = tid + k * 384;
            if (sl >= 1408) sl -= 1408;
            int row = sl >> 3, qq = sl & 7;
            ushort4 pk;
            pk.x = f2bf(ar[k].x); pk.y = f2bf(ar[k].y);
            pk.z = f2bf(ar[k].z); pk.w = f2bf(ar[k].w);
            *(ushort4*)(buf + (qq >> 1) * APL11 + row * 16 + (qq & 1) * 8) = pk;
        }
    };

    v4f acc[4][2] = {};
    v8bf bpipe[6][2];
    float4 areg[4];

    {   // prologue: A(0) issued first (oldest), then 12 B loads (taps 0..5)
        issueA(0, areg);
#pragma unroll
        for (int i = 0; i < 6; ++i) {
            const char* p = bbase + (size_t)i * SSTRIDE;
            bpipe[i][0] = *(const v8bf*)p;
            bpipe[i][1] = *(const v8bf*)(p + 256);
        }
        convertA(areg, ldsA);        // reg-dep waits areg (vmcnt<=12)
        BARRIER(12);                 // all 12 B prefetches stay in flight
    }

    // TAPC(S): compute tap (e,S); prefetch tap (e*9+S+6)'s 2 B frags.
#define TAPC(S) do { \
        v8bf b0 = bpipe[(S) % 6][0]; \
        v8bf b1 = bpipe[(S) % 6][1]; \
        const int _so = (((S) / 3) * 16 + ((S) % 3)) * 16; \
        v8bf a0 = *(const v8bf*)(Acur + aoff[0] + _so); \
        v8bf a1 = *(const v8bf*)(Acur + aoff[1] + _so); \
        v8bf a2 = *(const v8bf*)(Acur + aoff[2] + _so); \
        v8bf a3 = *(const v8bf*)(Acur + aoff[3] + _so); \
        __builtin_amdgcn_s_setprio(1); \
        acc[0][0] = __builtin_amdgcn_mfma_f32_16x16x32_bf16(a0, b0, acc[0][0], 0, 0, 0); \
        acc[0][1] = __builtin_amdgcn_mfma_f32_16x16x32_bf16(a0, b1, acc[0][1], 0, 0, 0); \
        acc[1][0] = __builtin_amdgcn_mfma_f32_16x16x32_bf16(a1, b0, acc[1][0], 0, 0, 0); \
        acc[1][1] = __builtin_amdgcn_mfma_f32_16x16x32_bf16(a1, b1, acc[1][1], 0, 0, 0); \
        acc[2][0] = __builtin_amdgcn_mfma_f32_16x16x32_bf16(a2, b0, acc[2][0], 0, 0, 0); \
        acc[2][1] = __builtin_amdgcn_mfma_f32_16x16x32_bf16(a2, b1, acc[2][1], 0, 0, 0); \
        acc[3][0] = __builtin_amdgcn_mfma_f32_16x16x32_bf16(a3, b0, acc[3][0], 0, 0, 0); \
        acc[3][1] = __builtin_amdgcn_mfma_f32_16x16x32_bf16(a3, b1, acc[3][1], 0, 0, 0); \
        __builtin_amdgcn_s_setprio(0); \
        if ((S) <= 2) { \
            const char* _p = bptr + (size_t)((S) + 6) * SSTRIDE; \
            bpipe[(S) % 6][0] = *(const v8bf*)_p; \
            bpipe[(S) % 6][1] = *(const v8bf*)(_p + 256); \
        } else if (e < 23) { \
            const char* _p = bptr + ESTRIDE + (size_t)((S) - 3) * SSTRIDE; \
            bpipe[(S) % 6][0] = *(const v8bf*)_p; \
            bpipe[(S) % 6][1] = *(const v8bf*)(_p + 256); \
        } \
    } while (0)

#pragma unroll 1
    for (int e = 0; e < 24; ++e) {
        const char* Acur = ldsA + (e & 1) * ABUF11;
        const char* bptr = bbase + (size_t)e * ESTRIDE;
        TAPC(0); TAPC(1); TAPC(2);
        if (e < 23) issueA(e + 1, areg);
        TAPC(3); TAPC(4); TAPC(5); TAPC(6);
        if (e < 23) convertA(areg, ldsA + ((e + 1) & 1) * ABUF11);  // waits areg (vmcnt<=8)
        TAPC(7); TAPC(8);
        if (e < 23) BARRIER(12);     // 12 B prefetches (taps 3..8) in flight
    }
#undef TAPC

    // ---- BN + gelu + dot(zpk) ----
    const float* bcp = conv ? bi    : br;
    const float* gp  = conv ? bni_g : bnr_g;
    const float* bbp = conv ? bni_b : bnr_b;
    const float* mp  = conv ? bni_m : bnr_m;
    const float* vp  = conv ? bni_v : bnr_v;

    float sum = 0.f;
#pragma unroll
    for (int nj = 0; nj < 2; ++nj) {
        const int o = nh * 192 + wid * 32 + nj * 16 + l15;
        const float sc  = gp[o] * rsqrtf(vp[o] + EPSF);
        const float sh2 = (bcp[o] - mp[o]) * sc + bbp[o];
        const u16* zb = zpk + ((size_t)b * 384 + o) * 64;
#pragma unroll
        for (int mi = 0; mi < 4; ++mi) {
            ushort4 zw = *(const ushort4*)(zb + mi * 16 + h * 4);
#pragma unroll
            for (int reg = 0; reg < 4; ++reg) {
                float y = fmaf(acc[mi][nj][reg], sc, sh2);
                u16 zu = (reg == 0) ? zw.x : (reg == 1) ? zw.y : (reg == 2) ? zw.z : zw.w;
                sum = fmaf(gelu_exact(y), bf2f(zu), sum);
            }
        }
    }
#pragma unroll
    for (int off = 32; off >= 1; off >>= 1) sum += __shfl_down(sum, off, 64);

    if (lane == 0) redF[wid] = sum;
    __syncthreads();
    if (tid == 0) {
        float t = redF[0] + redF[1] + redF[2] + redF[3] + redF[4] + redF[5];
        part[((size_t)conv * 128 + b) * 2 + nh] = t;
    }
}

// ---------------------------------------------------------------------------
// kr: combine n-half partials, sigmoid.
// ---------------------------------------------------------------------------
__global__ __launch_bounds__(256) void kr(const float* __restrict__ part,
                                          const float* __restrict__ c,
                                          float* __restrict__ out) {
    int v = threadIdx.x;     // 0..255 = conv*128+b
    float s = part[v * 2] + part[v * 2 + 1];
    out[v] = 1.f / (1.f + expf(-s / c[0]));
}

extern "C" void kernel_launch(void* const* d_in, const int* in_sizes, int n_in,
                              void* d_out, int out_size, void* d_ws, size_t ws_size,
                              hipStream_t stream) {
    const float* z_r   = (const float*)d_in[0];
    const float* z_i   = (const float*)d_in[1];
    const float* x_r   = (const float*)d_in[2];
    const float* x_i   = (const float*)d_in[3];
    const float* fz_w  = (const float*)d_in[4];
    const float* fz_b  = (const float*)d_in[5];
    const float* ln_g  = (const float*)d_in[6];
    const float* ln_b  = (const float*)d_in[7];
    const float* wr    = (const float*)d_in[8];
    const float* br    = (const float*)d_in[9];
    const float* bnr_g = (const float*)d_in[10];
    const float* bnr_b = (const float*)d_in[11];
    const float* bnr_m = (const float*)d_in[12];
    const float* bnr_v = (const float*)d_in[13];
    const float* wi    = (const float*)d_in[14];
    const float* bi    = (const float*)d_in[15];
    const float* bni_g = (const float*)d_in[16];
    const float* bni_b = (const float*)d_in[17];
    const float* bni_m = (const float*)d_in[18];
    const float* bni_v = (const float*)d_in[19];
    const float* c     = (const float*)d_in[20];

    // ws (bytes): Bz [0, 1179648) | Bw [+10616832) | zpk [+6291456) | part [+2048)
    u16*   Bz   = (u16*)d_ws;
    u16*   Bw   = (u16*)((char*)d_ws + 1179648);
    u16*   zpk  = (u16*)((char*)d_ws + 1179648 + 10616832);
    float* part = (float*)((char*)d_ws + 1179648 + 10616832 + 6291456);

    kprep_z<<<288, 256, 0, stream>>>(fz_w, Bz);
    kprep_w<<<768, 256, 0, stream>>>(wr, wi, Bw);
    kz2<<<dim3(2, 128), 384, 0, stream>>>(z_r, z_i, Bz, fz_b, ln_g, ln_b, zpk);
    kc11<<<dim3(4, 128), 384, 0, stream>>>(x_r, x_i, Bw, zpk,
                                           br, bnr_g, bnr_b, bnr_m, bnr_v,
                                           bi, bni_g, bni_b, bni_m, bni_v,
                                           part);
    kr<<<1, 256, 0, stream>>>(part, c, (float*)d_out);
}